// Round 1
// baseline (3312.372 us; speedup 1.0000x reference)
//
#include <hip/hip_runtime.h>
#include <hip/hip_bf16.h>

#define VN 786432
#define EN 6291456
#define KCH 5
#define FIN 16
#define FOUT 32

// ---------------- CSR build ----------------

__global__ void k_count(const int* __restrict__ rows, int* __restrict__ cnt) {
    int e = blockIdx.x * blockDim.x + threadIdx.x;
    if (e < EN) atomicAdd(&cnt[rows[e]], 1);
}

// Per-wave inclusive scan + one atomic grab per wave -> row segment starts.
// Segment ordering across waves is nondeterministic, which is fine: we only
// need each row to own a contiguous [start, start+cnt) range.
__global__ void k_scan(const int* __restrict__ cnt, int* __restrict__ row_start,
                       int* __restrict__ cursor, int* __restrict__ gcur) {
    int i = blockIdx.x * blockDim.x + threadIdx.x;
    int lane = threadIdx.x & 63;
    int c = (i < VN) ? cnt[i] : 0;
    int s = c;
    #pragma unroll
    for (int d = 1; d < 64; d <<= 1) {
        int t = __shfl_up(s, d);
        if (lane >= d) s += t;
    }
    int total = __shfl(s, 63);
    int base = 0;
    if (lane == 63) base = atomicAdd(gcur, total);
    base = __shfl(base, 63);
    int st = base + s - c;   // exclusive within wave + wave base
    if (i < VN) { row_start[i] = st; cursor[i] = st; }
}

__global__ void k_fill(const int* __restrict__ rows, const int* __restrict__ cols,
                       const float* __restrict__ vals, int* __restrict__ cursor,
                       int* __restrict__ csr_col, float* __restrict__ csr_val) {
    int e = blockIdx.x * blockDim.x + threadIdx.x;
    if (e >= EN) return;
    int r = rows[e];
    int p = atomicAdd(&cursor[r], 1);
    csr_col[p] = cols[e];
    csr_val[p] = vals[e];
}

// ---------------- SpMM + Chebyshev recurrence ----------------
// out = alpha * (L @ z) - prev   (prev == nullptr -> out = alpha * (L @ z))
// Thread per (row, float4 chunk). Chunk-threads of a row are adjacent lanes,
// so each edge's gather touches one contiguous 64B/128B line of z.

template<int F>
__global__ void k_spmm(const int* __restrict__ row_start, const int* __restrict__ cnt,
                       const int* __restrict__ csr_col, const float* __restrict__ csr_val,
                       const float* __restrict__ z, const float* __restrict__ prev,
                       float* __restrict__ out, float alpha) {
    constexpr int C = F / 4;
    int t = blockIdx.x * blockDim.x + threadIdx.x;
    int row = t / C, ch = t - row * C;
    if (row >= VN) return;
    int s = row_start[row], n = cnt[row];
    float4 acc = make_float4(0.f, 0.f, 0.f, 0.f);
    for (int j = 0; j < n; ++j) {
        int c = csr_col[s + j];
        float v = csr_val[s + j];
        const float4 zz = *reinterpret_cast<const float4*>(&z[c * F + ch * 4]);
        acc.x += v * zz.x; acc.y += v * zz.y; acc.z += v * zz.z; acc.w += v * zz.w;
    }
    int o = row * F + ch * 4;
    float4 r;
    if (prev != nullptr) {
        const float4 p = *reinterpret_cast<const float4*>(&prev[o]);
        r = make_float4(alpha * acc.x - p.x, alpha * acc.y - p.y,
                        alpha * acc.z - p.z, alpha * acc.w - p.w);
    } else {
        r = make_float4(alpha * acc.x, alpha * acc.y, alpha * acc.z, alpha * acc.w);
    }
    *reinterpret_cast<float4*>(&out[o]) = r;
}

// ---------------- per-term dense combine: h += x_k @ W_k ----------------
// weight index per reference layout: w[(f*K + k) * FOUT + fo]
// first==1: h = bias + contribution (initializes the re-poisoned buffer)

template<int F>
__global__ void k_combine(const float* __restrict__ xk, const float* __restrict__ w,
                          const float* __restrict__ bias, float* __restrict__ h,
                          int k, int first) {
    constexpr int C = FOUT / 4;   // 8 chunks of 4 outputs
    int t = blockIdx.x * blockDim.x + threadIdx.x;
    int row = t / C, ch = t - row * C;
    if (row >= VN) return;
    const float* xr = &xk[row * F];
    float4 acc;
    if (first) acc = *reinterpret_cast<const float4*>(&bias[ch * 4]);
    else       acc = *reinterpret_cast<const float4*>(&h[row * FOUT + ch * 4]);
    #pragma unroll
    for (int f = 0; f < F; ++f) {
        float xv = xr[f];
        const float4 wv = *reinterpret_cast<const float4*>(&w[(f * KCH + k) * FOUT + ch * 4]);
        acc.x += xv * wv.x; acc.y += xv * wv.y; acc.z += xv * wv.z; acc.w += xv * wv.w;
    }
    *reinterpret_cast<float4*>(&h[row * FOUT + ch * 4]) = acc;
}

// ---------------- ELU (in place, float4) ----------------

__global__ void k_elu(float* __restrict__ h, int n4) {
    int i = blockIdx.x * blockDim.x + threadIdx.x;
    if (i >= n4) return;
    float4 v = reinterpret_cast<float4*>(h)[i];
    v.x = v.x > 0.f ? v.x : (expf(v.x) - 1.f);
    v.y = v.y > 0.f ? v.y : (expf(v.y) - 1.f);
    v.z = v.z > 0.f ? v.z : (expf(v.z) - 1.f);
    v.w = v.w > 0.f ? v.w : (expf(v.w) - 1.f);
    reinterpret_cast<float4*>(h)[i] = v;
}

// ---------------- factor-4 max pool along vertex dim ----------------

__global__ void k_pool(const float* __restrict__ skip, float* __restrict__ pooled) {
    constexpr int C = FOUT / 4;
    int t = blockIdx.x * blockDim.x + threadIdx.x;
    int pv = t / C, ch = t - pv * C;
    if (pv >= VN / 4) return;
    const float4 a = *reinterpret_cast<const float4*>(&skip[(pv * 4 + 0) * FOUT + ch * 4]);
    const float4 b = *reinterpret_cast<const float4*>(&skip[(pv * 4 + 1) * FOUT + ch * 4]);
    const float4 c = *reinterpret_cast<const float4*>(&skip[(pv * 4 + 2) * FOUT + ch * 4]);
    const float4 d = *reinterpret_cast<const float4*>(&skip[(pv * 4 + 3) * FOUT + ch * 4]);
    float4 m;
    m.x = fmaxf(fmaxf(a.x, b.x), fmaxf(c.x, d.x));
    m.y = fmaxf(fmaxf(a.y, b.y), fmaxf(c.y, d.y));
    m.z = fmaxf(fmaxf(a.z, b.z), fmaxf(c.z, d.z));
    m.w = fmaxf(fmaxf(a.w, b.w), fmaxf(c.w, d.w));
    *reinterpret_cast<float4*>(&pooled[pv * FOUT + ch * 4]) = m;
}

extern "C" void kernel_launch(void* const* d_in, const int* in_sizes, int n_in,
                              void* d_out, int out_size, void* d_ws, size_t ws_size,
                              hipStream_t stream) {
    const float* x    = (const float*)d_in[0];
    const int*   rows = (const int*)  d_in[1];
    const int*   cols = (const int*)  d_in[2];
    const float* vals = (const float*)d_in[3];
    const float* w1   = (const float*)d_in[4];
    const float* b1   = (const float*)d_in[5];
    const float* w2   = (const float*)d_in[6];
    const float* b2   = (const float*)d_in[7];
    float* out = (float*)d_out;

    // workspace layout
    float* bufA    = (float*)d_ws;                       // V*32 floats
    float* bufB    = bufA + (size_t)VN * FOUT;           // V*32 floats
    float* h1      = bufB + (size_t)VN * FOUT;           // V*32 floats
    int*   csr_col = (int*)(h1 + (size_t)VN * FOUT);     // E ints
    float* csr_val = (float*)(csr_col + EN);             // E floats
    int*   row_start = (int*)(csr_val + EN);             // V ints
    int*   cnt     = row_start + VN;                     // V ints
    int*   cursor  = cnt + VN;                           // V ints
    int*   gcur    = cursor + VN;                        // 1 int

    hipMemsetAsync(cnt, 0, VN * sizeof(int), stream);
    hipMemsetAsync(gcur, 0, sizeof(int), stream);

    const int B256 = 256;
    // CSR build
    k_count<<<EN / B256, B256, 0, stream>>>(rows, cnt);
    k_scan <<<VN / B256, B256, 0, stream>>>(cnt, row_start, cursor, gcur);
    k_fill <<<EN / B256, B256, 0, stream>>>(rows, cols, vals, cursor, csr_col, csr_val);

    const int gSp16 = VN * (FIN / 4)  / B256;   // 12288
    const int gSp32 = VN * (FOUT / 4) / B256;   // 24576
    const int gCmb  = VN * (FOUT / 4) / B256;   // 24576
    const int gElu  = VN * FOUT / 4 / B256;     // 24576
    const int gPool = (VN / 4) * (FOUT / 4) / B256; // 6144

    // ---- layer 1 (F=16), h1 accumulates ----
    k_combine<FIN><<<gCmb, B256, 0, stream>>>(x,    w1, b1, h1, 0, 1);
    k_spmm<FIN><<<gSp16, B256, 0, stream>>>(row_start, cnt, csr_col, csr_val, x,    nullptr, bufA, 1.f);
    k_combine<FIN><<<gCmb, B256, 0, stream>>>(bufA, w1, b1, h1, 1, 0);
    k_spmm<FIN><<<gSp16, B256, 0, stream>>>(row_start, cnt, csr_col, csr_val, bufA, x,       bufB, 2.f);
    k_combine<FIN><<<gCmb, B256, 0, stream>>>(bufB, w1, b1, h1, 2, 0);
    k_spmm<FIN><<<gSp16, B256, 0, stream>>>(row_start, cnt, csr_col, csr_val, bufB, bufA,    bufA, 2.f);
    k_combine<FIN><<<gCmb, B256, 0, stream>>>(bufA, w1, b1, h1, 3, 0);
    k_spmm<FIN><<<gSp16, B256, 0, stream>>>(row_start, cnt, csr_col, csr_val, bufA, bufB,    bufB, 2.f);
    k_combine<FIN><<<gCmb, B256, 0, stream>>>(bufB, w1, b1, h1, 4, 0);
    k_elu<<<gElu, B256, 0, stream>>>(h1, VN * FOUT / 4);

    // ---- layer 2 (F=32), accumulate directly into d_out (skip region) ----
    k_combine<FOUT><<<gCmb, B256, 0, stream>>>(h1,   w2, b2, out, 0, 1);
    k_spmm<FOUT><<<gSp32, B256, 0, stream>>>(row_start, cnt, csr_col, csr_val, h1,   nullptr, bufA, 1.f);
    k_combine<FOUT><<<gCmb, B256, 0, stream>>>(bufA, w2, b2, out, 1, 0);
    k_spmm<FOUT><<<gSp32, B256, 0, stream>>>(row_start, cnt, csr_col, csr_val, bufA, h1,      bufB, 2.f);
    k_combine<FOUT><<<gCmb, B256, 0, stream>>>(bufB, w2, b2, out, 2, 0);
    k_spmm<FOUT><<<gSp32, B256, 0, stream>>>(row_start, cnt, csr_col, csr_val, bufB, bufA,    bufA, 2.f);
    k_combine<FOUT><<<gCmb, B256, 0, stream>>>(bufA, w2, b2, out, 3, 0);
    k_spmm<FOUT><<<gSp32, B256, 0, stream>>>(row_start, cnt, csr_col, csr_val, bufA, bufB,    bufB, 2.f);
    k_combine<FOUT><<<gCmb, B256, 0, stream>>>(bufB, w2, b2, out, 4, 0);
    k_elu<<<gElu, B256, 0, stream>>>(out, VN * FOUT / 4);

    // ---- pool: skip (d_out[0 : V*32)) -> pooled (d_out[V*32 : ...)) ----
    k_pool<<<gPool, B256, 0, stream>>>(out, out + (size_t)VN * FOUT);
}

// Round 2
// 2707.311 us; speedup vs baseline: 1.2235x; 1.2235x over previous
//
#include <hip/hip_runtime.h>
#include <hip/hip_bf16.h>

#define VN 786432
#define EN 6291456
#define KCH 5
#define FIN 16
#define FOUT 32

// ---------------- CSR build ----------------

__global__ void k_count(const int4* __restrict__ rows4, int* __restrict__ cnt) {
    int i = blockIdx.x * blockDim.x + threadIdx.x;   // i < EN/4
    int4 r = rows4[i];
    atomicAdd(&cnt[r.x], 1);
    atomicAdd(&cnt[r.y], 1);
    atomicAdd(&cnt[r.z], 1);
    atomicAdd(&cnt[r.w], 1);
}

// Per-wave inclusive scan + one atomic grab per wave -> row segment starts.
__global__ void k_scan(const int* __restrict__ cnt, int* __restrict__ row_start,
                       int* __restrict__ cursor, int* __restrict__ gcur) {
    int i = blockIdx.x * blockDim.x + threadIdx.x;
    int lane = threadIdx.x & 63;
    int c = cnt[i];
    int s = c;
    #pragma unroll
    for (int d = 1; d < 64; d <<= 1) {
        int t = __shfl_up(s, d);
        if (lane >= d) s += t;
    }
    int total = __shfl(s, 63);
    int base = 0;
    if (lane == 63) base = atomicAdd(gcur, total);
    base = __shfl(base, 63);
    int st = base + s - c;
    row_start[i] = st;
    cursor[i] = st;
}

// Packed fill: one 8B record per edge -> one dirty line per edge, not two.
__global__ void k_fill(const int4* __restrict__ rows4, const int4* __restrict__ cols4,
                       const float4* __restrict__ vals4, int* __restrict__ cursor,
                       int2* __restrict__ csr) {
    int i = blockIdx.x * blockDim.x + threadIdx.x;   // i < EN/4
    int4 r = rows4[i]; int4 c = cols4[i]; float4 v = vals4[i];
    int p;
    p = atomicAdd(&cursor[r.x], 1); csr[p] = make_int2(c.x, __float_as_int(v.x));
    p = atomicAdd(&cursor[r.y], 1); csr[p] = make_int2(c.y, __float_as_int(v.y));
    p = atomicAdd(&cursor[r.z], 1); csr[p] = make_int2(c.z, __float_as_int(v.z));
    p = atomicAdd(&cursor[r.w], 1); csr[p] = make_int2(c.w, __float_as_int(v.w));
}

// ---------------- fused SpMM + Chebyshev recurrence + combine ----------------
// FIRST (k=1): x1 = L@x;           h = bias + prev@W0 + x1@W1   (prev = x)
// MID   (k):   xk = 2*L@z - prev;  h += xk@Wk
// LAST  (k=4): same as MID, no xout write, ELU applied; POOL adds LDS max-pool.
// Thread per (row, 4-wide chunk). C lanes share a row; full xk row is
// collected via __shfl so each lane computes FOUT/C outputs of the combine.

template<int F, bool FIRST, bool LAST, bool POOL>
__global__ void k_spmm_fused(const int* __restrict__ row_start, const int* __restrict__ cnt,
                             const int2* __restrict__ csr,
                             const float* __restrict__ z, const float* __restrict__ prev,
                             const float* __restrict__ w, const float* __restrict__ bias,
                             float* __restrict__ h, float* __restrict__ xout,
                             float* __restrict__ pooled, int k) {
    constexpr int C = F / 4;            // lanes per row
    constexpr int HPL = FOUT / C;       // h outputs per lane (8 for F=16, 4 for F=32)
    __shared__ float lds[POOL ? (256 / (F / 4)) * FOUT : 1];

    int t = blockIdx.x * blockDim.x + threadIdx.x;
    int row = t / C, ch = t % C;        // grid exact, no bounds check
    int lane = threadIdx.x & 63;
    int gbase = lane & ~(C - 1);

    int s = row_start[row], n = cnt[row];
    float4 acc = make_float4(0.f, 0.f, 0.f, 0.f);
    for (int j = 0; j < n; ++j) {
        int2 e = csr[s + j];
        float v = __int_as_float(e.y);
        const float4 zz = *reinterpret_cast<const float4*>(&z[(size_t)e.x * F + ch * 4]);
        acc.x += v * zz.x; acc.y += v * zz.y; acc.z += v * zz.z; acc.w += v * zz.w;
    }
    const float4 pr = *reinterpret_cast<const float4*>(&prev[(size_t)row * F + ch * 4]);
    float4 xk;
    if (FIRST) {
        xk = acc;
    } else {
        xk = make_float4(2.f * acc.x - pr.x, 2.f * acc.y - pr.y,
                         2.f * acc.z - pr.z, 2.f * acc.w - pr.w);
    }
    if (!LAST) *reinterpret_cast<float4*>(&xout[(size_t)row * F + ch * 4]) = xk;

    // collect full xk row (and x row if FIRST) across the C lanes of this row
    float xr[F];
    float x0r[FIRST ? F : 1];
    #pragma unroll
    for (int c2 = 0; c2 < C; ++c2) {
        int src = gbase + c2;
        xr[c2 * 4 + 0] = __shfl(xk.x, src);
        xr[c2 * 4 + 1] = __shfl(xk.y, src);
        xr[c2 * 4 + 2] = __shfl(xk.z, src);
        xr[c2 * 4 + 3] = __shfl(xk.w, src);
        if (FIRST) {
            x0r[c2 * 4 + 0] = __shfl(pr.x, src);
            x0r[c2 * 4 + 1] = __shfl(pr.y, src);
            x0r[c2 * 4 + 2] = __shfl(pr.z, src);
            x0r[c2 * 4 + 3] = __shfl(pr.w, src);
        }
    }

    int fo0 = ch * HPL;
    float hacc[HPL];
    if (FIRST) {
        #pragma unroll
        for (int i = 0; i < HPL; ++i) hacc[i] = bias[fo0 + i];
    } else {
        #pragma unroll
        for (int i = 0; i < HPL; i += 4) {
            float4 hv = *reinterpret_cast<const float4*>(&h[(size_t)row * FOUT + fo0 + i]);
            hacc[i] = hv.x; hacc[i + 1] = hv.y; hacc[i + 2] = hv.z; hacc[i + 3] = hv.w;
        }
    }
    #pragma unroll
    for (int f = 0; f < F; ++f) {
        const float* wrow = &w[(f * KCH + k) * FOUT + fo0];
        #pragma unroll
        for (int i = 0; i < HPL; ++i) hacc[i] += xr[f] * wrow[i];
    }
    if (FIRST) {
        #pragma unroll
        for (int f = 0; f < F; ++f) {
            const float* wrow = &w[(f * KCH + 0) * FOUT + fo0];
            #pragma unroll
            for (int i = 0; i < HPL; ++i) hacc[i] += x0r[f] * wrow[i];
        }
    }
    if (LAST) {
        #pragma unroll
        for (int i = 0; i < HPL; ++i)
            hacc[i] = hacc[i] > 0.f ? hacc[i] : (expf(hacc[i]) - 1.f);
    }
    #pragma unroll
    for (int i = 0; i < HPL; i += 4) {
        *reinterpret_cast<float4*>(&h[(size_t)row * FOUT + fo0 + i]) =
            make_float4(hacc[i], hacc[i + 1], hacc[i + 2], hacc[i + 3]);
    }
    if (POOL) {
        int rl = threadIdx.x / C;                 // local row 0..31
        #pragma unroll
        for (int i = 0; i < HPL; ++i) lds[rl * FOUT + fo0 + i] = hacc[i];
        __syncthreads();
        int pvl = threadIdx.x >> 5;               // 0..7 pool groups per block
        int f = threadIdx.x & 31;
        float m = lds[(pvl * 4 + 0) * FOUT + f];
        m = fmaxf(m, lds[(pvl * 4 + 1) * FOUT + f]);
        m = fmaxf(m, lds[(pvl * 4 + 2) * FOUT + f]);
        m = fmaxf(m, lds[(pvl * 4 + 3) * FOUT + f]);
        pooled[(size_t)(blockIdx.x * 8 + pvl) * FOUT + f] = m;
    }
}

extern "C" void kernel_launch(void* const* d_in, const int* in_sizes, int n_in,
                              void* d_out, int out_size, void* d_ws, size_t ws_size,
                              hipStream_t stream) {
    const float* x    = (const float*)d_in[0];
    const int*   rows = (const int*)  d_in[1];
    const int*   cols = (const int*)  d_in[2];
    const float* vals = (const float*)d_in[3];
    const float* w1   = (const float*)d_in[4];
    const float* b1   = (const float*)d_in[5];
    const float* w2   = (const float*)d_in[6];
    const float* b2   = (const float*)d_in[7];
    float* out = (float*)d_out;

    // workspace layout
    float* bufA      = (float*)d_ws;                     // V*32 floats
    float* bufB      = bufA + (size_t)VN * FOUT;         // V*32 floats
    float* h1        = bufB + (size_t)VN * FOUT;         // V*32 floats
    int2*  csr       = (int2*)(h1 + (size_t)VN * FOUT);  // E * 8B
    int*   row_start = (int*)(csr + EN);                 // V ints
    int*   cnt       = row_start + VN;                   // V ints
    int*   cursor    = cnt + VN;                         // V ints
    int*   gcur      = cursor + VN;                      // 1 int

    hipMemsetAsync(cnt, 0, VN * sizeof(int), stream);
    hipMemsetAsync(gcur, 0, sizeof(int), stream);

    const int B = 256;
    k_count<<<EN / 4 / B, B, 0, stream>>>((const int4*)rows, cnt);
    k_scan <<<VN / B, B, 0, stream>>>(cnt, row_start, cursor, gcur);
    k_fill <<<EN / 4 / B, B, 0, stream>>>((const int4*)rows, (const int4*)cols,
                                          (const float4*)vals, cursor, csr);

    const int g16 = VN * (FIN / 4) / B;    // 12288
    const int g32 = VN * (FOUT / 4) / B;   // 24576

    // ---- layer 1 (F=16): h1 accumulated in fused epilogues ----
    k_spmm_fused<FIN, true,  false, false><<<g16, B, 0, stream>>>(
        row_start, cnt, csr, x,    x,    w1, b1, h1, bufA, nullptr, 1);
    k_spmm_fused<FIN, false, false, false><<<g16, B, 0, stream>>>(
        row_start, cnt, csr, bufA, x,    w1, b1, h1, bufB, nullptr, 2);
    k_spmm_fused<FIN, false, false, false><<<g16, B, 0, stream>>>(
        row_start, cnt, csr, bufB, bufA, w1, b1, h1, bufA, nullptr, 3);
    k_spmm_fused<FIN, false, true,  false><<<g16, B, 0, stream>>>(
        row_start, cnt, csr, bufA, bufB, w1, b1, h1, nullptr, nullptr, 4);   // + ELU

    // ---- layer 2 (F=32): accumulate into d_out (skip region) ----
    k_spmm_fused<FOUT, true,  false, false><<<g32, B, 0, stream>>>(
        row_start, cnt, csr, h1,   h1,   w2, b2, out, bufA, nullptr, 1);
    k_spmm_fused<FOUT, false, false, false><<<g32, B, 0, stream>>>(
        row_start, cnt, csr, bufA, h1,   w2, b2, out, bufB, nullptr, 2);
    k_spmm_fused<FOUT, false, false, false><<<g32, B, 0, stream>>>(
        row_start, cnt, csr, bufB, bufA, w2, b2, out, bufA, nullptr, 3);
    k_spmm_fused<FOUT, false, true,  true ><<<g32, B, 0, stream>>>(
        row_start, cnt, csr, bufA, bufB, w2, b2, out, nullptr,
        out + (size_t)VN * FOUT, 4);                                          // + ELU + pool
}

// Round 4
// 2639.345 us; speedup vs baseline: 1.2550x; 1.0258x over previous
//
#include <hip/hip_runtime.h>
#include <hip/hip_bf16.h>

#define VN 786432
#define EN 6291456
#define KCH 5
#define FIN 16
#define FOUT 32

// ---- bf16 helpers (RNE pack, bit-exact unpack) ----
__device__ inline float blo(unsigned u) { return __uint_as_float(u << 16); }
__device__ inline float bhi(unsigned u) { return __uint_as_float(u & 0xffff0000u); }
__device__ inline unsigned bpack(float lo, float hi) {
    unsigned ul = __float_as_uint(lo), uh = __float_as_uint(hi);
    ul = (ul + 0x7fffu + ((ul >> 16) & 1u)) >> 16;
    uh = (uh + 0x7fffu + ((uh >> 16) & 1u)) & 0xffff0000u;
    return ul | uh;
}

// ---------------- CSR build (R2-proven: count / wave-scan / fill) ----------------

__global__ void k_count(const int4* __restrict__ rows4, int* __restrict__ cnt) {
    int i = blockIdx.x * blockDim.x + threadIdx.x;   // i < EN/4
    int4 r = rows4[i];
    atomicAdd(&cnt[r.x], 1);
    atomicAdd(&cnt[r.y], 1);
    atomicAdd(&cnt[r.z], 1);
    atomicAdd(&cnt[r.w], 1);
}

__global__ void k_scan(const int* __restrict__ cnt, int* __restrict__ row_start,
                       int* __restrict__ cursor, int* __restrict__ gcur) {
    int i = blockIdx.x * blockDim.x + threadIdx.x;
    int lane = threadIdx.x & 63;
    int c = (i < VN) ? cnt[i] : 0;
    int s = c;
    #pragma unroll
    for (int d = 1; d < 64; d <<= 1) {
        int t = __shfl_up(s, d);
        if (lane >= d) s += t;
    }
    int total = __shfl(s, 63);
    int base = 0;
    if (lane == 63) base = atomicAdd(gcur, total);
    base = __shfl(base, 63);
    int st = base + s - c;
    if (i < VN) { row_start[i] = st; cursor[i] = st; }
}

__global__ void k_fill(const int4* __restrict__ rows4, const int4* __restrict__ cols4,
                       const float4* __restrict__ vals4, int* __restrict__ cursor,
                       int2* __restrict__ csr) {
    int i = blockIdx.x * blockDim.x + threadIdx.x;   // i < EN/4
    int4 r = rows4[i]; int4 c = cols4[i]; float4 v = vals4[i];
    int p;
    p = atomicAdd(&cursor[r.x], 1); csr[p] = make_int2(c.x, __float_as_int(v.x));
    p = atomicAdd(&cursor[r.y], 1); csr[p] = make_int2(c.y, __float_as_int(v.y));
    p = atomicAdd(&cursor[r.z], 1); csr[p] = make_int2(c.z, __float_as_int(v.z));
    p = atomicAdd(&cursor[r.w], 1); csr[p] = make_int2(c.w, __float_as_int(v.w));
}

// ---------------- fp32 -> bf16 input conversion ----------------
__global__ void k_cvt(const float4* __restrict__ xf, uint4* __restrict__ xb) {
    int i = blockIdx.x * blockDim.x + threadIdx.x;   // handles 8 floats
    float4 a = xf[2 * i], b = xf[2 * i + 1];
    uint4 o;
    o.x = bpack(a.x, a.y); o.y = bpack(a.z, a.w);
    o.z = bpack(b.x, b.y); o.w = bpack(b.z, b.w);
    xb[i] = o;
}

// ---------------- fused SpMM (bf16 in) + recurrence + combine ----------------
// FIRST: x1 = L@x;          h = bias + x@W0 + x1@W1
// MID:   xk = 2*L@z - prev; h += xk@Wk
// LAST:  like MID, no xout; + ELU; HOUT_BF writes bf16 h1; POOL adds max-pool.
// Lane owns an 8-bf16 chunk (16B). C = F/8 lanes per row.
// NOTE: no __restrict__ on zb/prevb/xoutb/h/h1b/pooled — buffers may be reused
// across launches; each is a distinct region within a launch (3-way rotation).

template<int F, bool FIRST, bool LAST, bool HOUT_BF, bool POOL>
__global__ void k_spmm(const int* __restrict__ row_start, const int* __restrict__ cnt,
                       const int2* __restrict__ csr,
                       const uint4* zb, const uint4* prevb,
                       const float* __restrict__ w, const float* __restrict__ bias,
                       float* h, uint4* xoutb,
                       uint4* h1b, float* pooled, int k) {
    constexpr int C = F / 8;                 // 2 (F=16) or 4 (F=32)
    constexpr int LC = (C == 2) ? 1 : 2;
    constexpr int HPL = FOUT / C;            // 16 or 8
    __shared__ float lds[POOL ? (256 / C) * FOUT : 1];

    int t = blockIdx.x * blockDim.x + threadIdx.x;
    int row = t >> LC, ch = t & (C - 1);
    int lane = threadIdx.x & 63;
    int gbase = lane & ~(C - 1);

    int s = row_start[row], n = cnt[row];
    float acc[8];
    #pragma unroll
    for (int q = 0; q < 8; ++q) acc[q] = 0.f;
    for (int j = 0; j < n; ++j) {
        int2 e = csr[s + j];
        float v = __int_as_float(e.y);
        uint4 zz = zb[(size_t)e.x * C + ch];
        acc[0] += v * blo(zz.x); acc[1] += v * bhi(zz.x);
        acc[2] += v * blo(zz.y); acc[3] += v * bhi(zz.y);
        acc[4] += v * blo(zz.z); acc[5] += v * bhi(zz.z);
        acc[6] += v * blo(zz.w); acc[7] += v * bhi(zz.w);
    }
    uint4 pv = prevb[(size_t)row * C + ch];
    float pr[8] = { blo(pv.x), bhi(pv.x), blo(pv.y), bhi(pv.y),
                    blo(pv.z), bhi(pv.z), blo(pv.w), bhi(pv.w) };
    float xk[8];
    #pragma unroll
    for (int q = 0; q < 8; ++q) xk[q] = FIRST ? acc[q] : 2.f * acc[q] - pr[q];
    if (!LAST) {
        uint4 o;
        o.x = bpack(xk[0], xk[1]); o.y = bpack(xk[2], xk[3]);
        o.z = bpack(xk[4], xk[5]); o.w = bpack(xk[6], xk[7]);
        xoutb[(size_t)row * C + ch] = o;
    }

    // gather full xk row (and x0 row if FIRST) across the C lanes of this row
    float xr[F];
    float x0r[FIRST ? F : 1];
    #pragma unroll
    for (int c2 = 0; c2 < C; ++c2) {
        #pragma unroll
        for (int q = 0; q < 8; ++q) {
            xr[c2 * 8 + q] = __shfl(xk[q], gbase + c2);
            if (FIRST) x0r[c2 * 8 + q] = __shfl(pr[q], gbase + c2);
        }
    }

    int fo0 = ch * HPL;
    float hacc[HPL];
    if (FIRST) {
        #pragma unroll
        for (int i = 0; i < HPL; ++i) hacc[i] = bias[fo0 + i];
    } else {
        #pragma unroll
        for (int i = 0; i < HPL; i += 4) {
            float4 hv = *reinterpret_cast<const float4*>(&h[(size_t)row * FOUT + fo0 + i]);
            hacc[i] = hv.x; hacc[i + 1] = hv.y; hacc[i + 2] = hv.z; hacc[i + 3] = hv.w;
        }
    }
    #pragma unroll
    for (int f = 0; f < F; ++f) {
        const float* wrow = &w[(f * KCH + k) * FOUT + fo0];
        #pragma unroll
        for (int i = 0; i < HPL; ++i) hacc[i] += xr[f] * wrow[i];
    }
    if (FIRST) {
        #pragma unroll
        for (int f = 0; f < F; ++f) {
            const float* wrow = &w[(f * KCH + 0) * FOUT + fo0];
            #pragma unroll
            for (int i = 0; i < HPL; ++i) hacc[i] += x0r[f] * wrow[i];
        }
    }
    if (LAST) {
        #pragma unroll
        for (int i = 0; i < HPL; ++i)
            hacc[i] = hacc[i] > 0.f ? hacc[i] : (expf(hacc[i]) - 1.f);
    }
    if (LAST && HOUT_BF) {
        // HPL==16 here: 2 uint4 per lane
        uint4 o0, o1;
        o0.x = bpack(hacc[0], hacc[1]);  o0.y = bpack(hacc[2], hacc[3]);
        o0.z = bpack(hacc[4], hacc[5]);  o0.w = bpack(hacc[6], hacc[7]);
        o1.x = bpack(hacc[8], hacc[9]);  o1.y = bpack(hacc[10], hacc[11]);
        o1.z = bpack(hacc[12], hacc[13]); o1.w = bpack(hacc[14], hacc[15]);
        h1b[(size_t)row * (FOUT / 8) + ch * 2 + 0] = o0;
        h1b[(size_t)row * (FOUT / 8) + ch * 2 + 1] = o1;
    } else {
        #pragma unroll
        for (int i = 0; i < HPL; i += 4) {
            *reinterpret_cast<float4*>(&h[(size_t)row * FOUT + fo0 + i]) =
                make_float4(hacc[i], hacc[i + 1], hacc[i + 2], hacc[i + 3]);
        }
    }
    if (POOL) {
        int rl = threadIdx.x >> LC;                 // local row 0..63
        #pragma unroll
        for (int i = 0; i < HPL; ++i) lds[rl * FOUT + fo0 + i] = hacc[i];
        __syncthreads();
        int pvl = threadIdx.x >> 4;                 // 16 pool groups per block
        int f0 = (threadIdx.x & 15) * 2;
        #pragma unroll
        for (int u = 0; u < 2; ++u) {
            int f = f0 + u;
            float m = lds[(pvl * 4 + 0) * FOUT + f];
            m = fmaxf(m, lds[(pvl * 4 + 1) * FOUT + f]);
            m = fmaxf(m, lds[(pvl * 4 + 2) * FOUT + f]);
            m = fmaxf(m, lds[(pvl * 4 + 3) * FOUT + f]);
            pooled[(size_t)(blockIdx.x * 16 + pvl) * FOUT + f] = m;
        }
    }
}

extern "C" void kernel_launch(void* const* d_in, const int* in_sizes, int n_in,
                              void* d_out, int out_size, void* d_ws, size_t ws_size,
                              hipStream_t stream) {
    const float* x    = (const float*)d_in[0];
    const int*   rows = (const int*)  d_in[1];
    const int*   cols = (const int*)  d_in[2];
    const float* vals = (const float*)d_in[3];
    const float* w1   = (const float*)d_in[4];
    const float* b1   = (const float*)d_in[5];
    const float* w2   = (const float*)d_in[6];
    const float* b2   = (const float*)d_in[7];
    float* out = (float*)d_out;

    // ---- workspace layout (total ~311.4 MB) ----
    char* p = (char*)d_ws;
    int2*  csr = (int2*)p;  p += (size_t)EN * 8;            // 50.33 MB
    uint4* xb  = (uint4*)p; p += (size_t)VN * FIN * 2;      // 25.17 MB
    // Shared region R: layer-1 {h1f, t0, t1, t2} then layer-2 {u0, u1, u2}.
    // h1f/t* are dead before any u* is written (L2k1 runs after L1k4).
    char* R = p;            p += (size_t)176160768;         // 176.16 MB
    float* h1f = (float*)R;                                 // VN*32 fp32 = 100.66 MB
    uint4* t0  = (uint4*)(R + 100663296);                   // VN*16 bf16 = 25.17 MB
    uint4* t1  = (uint4*)(R + 125829120);
    uint4* t2  = (uint4*)(R + 150994944);
    uint4* u0  = (uint4*)R;                                 // VN*32 bf16 = 50.33 MB
    uint4* u1  = (uint4*)(R + 50331648);
    uint4* u2  = (uint4*)(R + 100663296);
    uint4* h1b = (uint4*)p; p += (size_t)VN * FOUT * 2;     // 50.33 MB
    int* row_start = (int*)p; p += (size_t)VN * 4;
    int* cnt       = (int*)p; p += (size_t)VN * 4;
    int* cursor    = (int*)p; p += (size_t)VN * 4;
    int* gcur      = (int*)p;

    hipMemsetAsync(cnt, 0, VN * sizeof(int), stream);
    hipMemsetAsync(gcur, 0, sizeof(int), stream);

    const int B = 256;
    k_count<<<EN / 4 / B, B, 0, stream>>>((const int4*)rows, cnt);
    k_scan <<<VN / B, B, 0, stream>>>(cnt, row_start, cursor, gcur);
    k_fill <<<EN / 4 / B, B, 0, stream>>>((const int4*)rows, (const int4*)cols,
                                          (const float4*)vals, cursor, csr);

    k_cvt<<<VN * FIN / 8 / B, B, 0, stream>>>((const float4*)x, xb);

    const int g16 = VN * 2 / B;   // 6144
    const int g32 = VN * 4 / B;   // 12288

    // ---- layer 1 (F=16), fp32 accum h1f, final bf16 h1b ----
    k_spmm<FIN, true,  false, false, false><<<g16, B, 0, stream>>>(
        row_start, cnt, csr, xb, xb, w1, b1, h1f, t0, nullptr, nullptr, 1);
    k_spmm<FIN, false, false, false, false><<<g16, B, 0, stream>>>(
        row_start, cnt, csr, t0, xb, w1, b1, h1f, t1, nullptr, nullptr, 2);
    k_spmm<FIN, false, false, false, false><<<g16, B, 0, stream>>>(
        row_start, cnt, csr, t1, t0, w1, b1, h1f, t2, nullptr, nullptr, 3);
    k_spmm<FIN, false, true,  true,  false><<<g16, B, 0, stream>>>(
        row_start, cnt, csr, t2, t1, w1, b1, h1f, nullptr, h1b, nullptr, 4); // +ELU ->bf16

    // ---- layer 2 (F=32), accumulate into d_out ----
    k_spmm<FOUT, true,  false, false, false><<<g32, B, 0, stream>>>(
        row_start, cnt, csr, h1b, h1b, w2, b2, out, u0, nullptr, nullptr, 1);
    k_spmm<FOUT, false, false, false, false><<<g32, B, 0, stream>>>(
        row_start, cnt, csr, u0, h1b, w2, b2, out, u1, nullptr, nullptr, 2);
    k_spmm<FOUT, false, false, false, false><<<g32, B, 0, stream>>>(
        row_start, cnt, csr, u1, u0, w2, b2, out, u2, nullptr, nullptr, 3);
    k_spmm<FOUT, false, true,  false, true ><<<g32, B, 0, stream>>>(
        row_start, cnt, csr, u2, u1, w2, b2, out, nullptr, nullptr,
        out + (size_t)VN * FOUT, 4);                                          // +ELU+pool
}

// Round 5
// 2540.547 us; speedup vs baseline: 1.3038x; 1.0389x over previous
//
#include <hip/hip_runtime.h>
#include <hip/hip_bf16.h>

#define VN 786432
#define EN 6291456
#define KCH 5
#define FIN 16
#define FOUT 32

// ---- bf16 helpers (RNE pack, bit-exact unpack) ----
__device__ inline float blo(unsigned u) { return __uint_as_float(u << 16); }
__device__ inline float bhi(unsigned u) { return __uint_as_float(u & 0xffff0000u); }
__device__ inline unsigned bpack(float lo, float hi) {
    unsigned ul = __float_as_uint(lo), uh = __float_as_uint(hi);
    ul = (ul + 0x7fffu + ((ul >> 16) & 1u)) >> 16;
    uh = (uh + 0x7fffu + ((uh >> 16) & 1u)) & 0xffff0000u;
    return ul | uh;
}

// ---------------- CSR build (R2-proven: count / wave-scan / fill) ----------------

__global__ void k_count(const int4* __restrict__ rows4, int* __restrict__ cnt) {
    int i = blockIdx.x * blockDim.x + threadIdx.x;   // i < EN/4
    int4 r = rows4[i];
    atomicAdd(&cnt[r.x], 1);
    atomicAdd(&cnt[r.y], 1);
    atomicAdd(&cnt[r.z], 1);
    atomicAdd(&cnt[r.w], 1);
}

__global__ void k_scan(const int* __restrict__ cnt, int* __restrict__ row_start,
                       int* __restrict__ cursor, int* __restrict__ gcur) {
    int i = blockIdx.x * blockDim.x + threadIdx.x;
    int lane = threadIdx.x & 63;
    int c = (i < VN) ? cnt[i] : 0;
    int s = c;
    #pragma unroll
    for (int d = 1; d < 64; d <<= 1) {
        int t = __shfl_up(s, d);
        if (lane >= d) s += t;
    }
    int total = __shfl(s, 63);
    int base = 0;
    if (lane == 63) base = atomicAdd(gcur, total);
    base = __shfl(base, 63);
    int st = base + s - c;
    if (i < VN) { row_start[i] = st; cursor[i] = st; }
}

__global__ void k_fill(const int4* __restrict__ rows4, const int4* __restrict__ cols4,
                       const float4* __restrict__ vals4, int* __restrict__ cursor,
                       int2* __restrict__ csr) {
    int i = blockIdx.x * blockDim.x + threadIdx.x;   // i < EN/4
    int4 r = rows4[i]; int4 c = cols4[i]; float4 v = vals4[i];
    int p;
    p = atomicAdd(&cursor[r.x], 1); csr[p] = make_int2(c.x, __float_as_int(v.x));
    p = atomicAdd(&cursor[r.y], 1); csr[p] = make_int2(c.y, __float_as_int(v.y));
    p = atomicAdd(&cursor[r.z], 1); csr[p] = make_int2(c.z, __float_as_int(v.z));
    p = atomicAdd(&cursor[r.w], 1); csr[p] = make_int2(c.w, __float_as_int(v.w));
}

// ---------------- fp32 -> bf16 input conversion ----------------
__global__ void k_cvt(const float4* __restrict__ xf, uint4* __restrict__ xb) {
    int i = blockIdx.x * blockDim.x + threadIdx.x;   // handles 8 floats
    float4 a = xf[2 * i], b = xf[2 * i + 1];
    uint4 o;
    o.x = bpack(a.x, a.y); o.y = bpack(a.z, a.w);
    o.z = bpack(b.x, b.y); o.w = bpack(b.z, b.w);
    xb[i] = o;
}

// ---------------- fused SpMM (bf16 in) + recurrence + combine ----------------
// FIRST: x1 = L@x;          h = bias + x@W0 + x1@W1
// MID:   xk = 2*L@z - prev; h += xk@Wk
// LAST:  like MID, no xout; + ELU; HOUT_BF writes bf16 h1; POOL adds max-pool.
// Lane owns an 8-bf16 chunk (16B). C = F/8 lanes per row.
// Edge loop is batched by 8: 8 independent csr loads, then 8 independent
// gathers in flight (MLP), then fma. Tail entries are masked with val=0 and
// redirected to the row's first column (same line -> free).

template<int F, bool FIRST, bool LAST, bool HOUT_BF, bool POOL>
__global__ void k_spmm(const int* __restrict__ row_start, const int* __restrict__ cnt,
                       const int2* __restrict__ csr,
                       const uint4* zb, const uint4* prevb,
                       const float* __restrict__ w, const float* __restrict__ bias,
                       float* h, uint4* xoutb,
                       uint4* h1b, float* pooled, int k) {
    constexpr int C = F / 8;                 // 2 (F=16) or 4 (F=32)
    constexpr int LC = (C == 2) ? 1 : 2;
    constexpr int HPL = FOUT / C;            // 16 or 8
    constexpr int U = 8;                     // edge batch size
    __shared__ float lds[POOL ? (256 / C) * FOUT : 1];

    int t = blockIdx.x * blockDim.x + threadIdx.x;
    int row = t >> LC, ch = t & (C - 1);
    int lane = threadIdx.x & 63;
    int gbase = lane & ~(C - 1);

    int s = row_start[row], n = cnt[row];
    float acc[8];
    #pragma unroll
    for (int q = 0; q < 8; ++q) acc[q] = 0.f;

    if (n > 0) {
        int csafe = csr[s].x;                // first col of row (n>=1)
        for (int j = 0; j < n; j += U) {
            int   ce[U];
            float vf[U];
            #pragma unroll
            for (int u = 0; u < U; ++u) {
                bool ok = (j + u) < n;
                int2 e = csr[ok ? (s + j + u) : s];
                ce[u] = ok ? e.x : csafe;
                vf[u] = ok ? __int_as_float(e.y) : 0.f;
            }
            uint4 g[U];
            #pragma unroll
            for (int u = 0; u < U; ++u)
                g[u] = zb[(size_t)ce[u] * C + ch];
            #pragma unroll
            for (int u = 0; u < U; ++u) {
                float v = vf[u];
                acc[0] += v * blo(g[u].x); acc[1] += v * bhi(g[u].x);
                acc[2] += v * blo(g[u].y); acc[3] += v * bhi(g[u].y);
                acc[4] += v * blo(g[u].z); acc[5] += v * bhi(g[u].z);
                acc[6] += v * blo(g[u].w); acc[7] += v * bhi(g[u].w);
            }
        }
    }

    uint4 pv = prevb[(size_t)row * C + ch];
    float pr[8] = { blo(pv.x), bhi(pv.x), blo(pv.y), bhi(pv.y),
                    blo(pv.z), bhi(pv.z), blo(pv.w), bhi(pv.w) };
    float xk[8];
    #pragma unroll
    for (int q = 0; q < 8; ++q) xk[q] = FIRST ? acc[q] : 2.f * acc[q] - pr[q];
    if (!LAST) {
        uint4 o;
        o.x = bpack(xk[0], xk[1]); o.y = bpack(xk[2], xk[3]);
        o.z = bpack(xk[4], xk[5]); o.w = bpack(xk[6], xk[7]);
        xoutb[(size_t)row * C + ch] = o;
    }

    // gather full xk row (and x0 row if FIRST) across the C lanes of this row
    float xr[F];
    float x0r[FIRST ? F : 1];
    #pragma unroll
    for (int c2 = 0; c2 < C; ++c2) {
        #pragma unroll
        for (int q = 0; q < 8; ++q) {
            xr[c2 * 8 + q] = __shfl(xk[q], gbase + c2);
            if (FIRST) x0r[c2 * 8 + q] = __shfl(pr[q], gbase + c2);
        }
    }

    int fo0 = ch * HPL;
    float hacc[HPL];
    if (FIRST) {
        #pragma unroll
        for (int i = 0; i < HPL; ++i) hacc[i] = bias[fo0 + i];
    } else {
        #pragma unroll
        for (int i = 0; i < HPL; i += 4) {
            float4 hv = *reinterpret_cast<const float4*>(&h[(size_t)row * FOUT + fo0 + i]);
            hacc[i] = hv.x; hacc[i + 1] = hv.y; hacc[i + 2] = hv.z; hacc[i + 3] = hv.w;
        }
    }
    #pragma unroll
    for (int f = 0; f < F; ++f) {
        const float* wrow = &w[(f * KCH + k) * FOUT + fo0];
        #pragma unroll
        for (int i = 0; i < HPL; ++i) hacc[i] += xr[f] * wrow[i];
    }
    if (FIRST) {
        #pragma unroll
        for (int f = 0; f < F; ++f) {
            const float* wrow = &w[(f * KCH + 0) * FOUT + fo0];
            #pragma unroll
            for (int i = 0; i < HPL; ++i) hacc[i] += x0r[f] * wrow[i];
        }
    }
    if (LAST) {
        #pragma unroll
        for (int i = 0; i < HPL; ++i)
            hacc[i] = hacc[i] > 0.f ? hacc[i] : (expf(hacc[i]) - 1.f);
    }
    if (LAST && HOUT_BF) {
        // HPL==16 here: 2 uint4 per lane
        uint4 o0, o1;
        o0.x = bpack(hacc[0], hacc[1]);  o0.y = bpack(hacc[2], hacc[3]);
        o0.z = bpack(hacc[4], hacc[5]);  o0.w = bpack(hacc[6], hacc[7]);
        o1.x = bpack(hacc[8], hacc[9]);  o1.y = bpack(hacc[10], hacc[11]);
        o1.z = bpack(hacc[12], hacc[13]); o1.w = bpack(hacc[14], hacc[15]);
        h1b[(size_t)row * (FOUT / 8) + ch * 2 + 0] = o0;
        h1b[(size_t)row * (FOUT / 8) + ch * 2 + 1] = o1;
    } else {
        #pragma unroll
        for (int i = 0; i < HPL; i += 4) {
            *reinterpret_cast<float4*>(&h[(size_t)row * FOUT + fo0 + i]) =
                make_float4(hacc[i], hacc[i + 1], hacc[i + 2], hacc[i + 3]);
        }
    }
    if (POOL) {
        int rl = threadIdx.x >> LC;                 // local row 0..63
        #pragma unroll
        for (int i = 0; i < HPL; ++i) lds[rl * FOUT + fo0 + i] = hacc[i];
        __syncthreads();
        int pvl = threadIdx.x >> 4;                 // 16 pool groups per block
        int f0 = (threadIdx.x & 15) * 2;
        #pragma unroll
        for (int u = 0; u < 2; ++u) {
            int f = f0 + u;
            float m = lds[(pvl * 4 + 0) * FOUT + f];
            m = fmaxf(m, lds[(pvl * 4 + 1) * FOUT + f]);
            m = fmaxf(m, lds[(pvl * 4 + 2) * FOUT + f]);
            m = fmaxf(m, lds[(pvl * 4 + 3) * FOUT + f]);
            pooled[(size_t)(blockIdx.x * 16 + pvl) * FOUT + f] = m;
        }
    }
}

extern "C" void kernel_launch(void* const* d_in, const int* in_sizes, int n_in,
                              void* d_out, int out_size, void* d_ws, size_t ws_size,
                              hipStream_t stream) {
    const float* x    = (const float*)d_in[0];
    const int*   rows = (const int*)  d_in[1];
    const int*   cols = (const int*)  d_in[2];
    const float* vals = (const float*)d_in[3];
    const float* w1   = (const float*)d_in[4];
    const float* b1   = (const float*)d_in[5];
    const float* w2   = (const float*)d_in[6];
    const float* b2   = (const float*)d_in[7];
    float* out = (float*)d_out;

    // ---- workspace layout (total ~311.4 MB) ----
    char* p = (char*)d_ws;
    int2*  csr = (int2*)p;  p += (size_t)EN * 8;            // 50.33 MB
    uint4* xb  = (uint4*)p; p += (size_t)VN * FIN * 2;      // 25.17 MB
    // Shared region R: layer-1 {h1f, t0, t1, t2} then layer-2 {u0, u1, u2}.
    // h1f/t* are dead before any u* is written (L2k1 runs after L1k4).
    char* R = p;            p += (size_t)176160768;         // 176.16 MB
    float* h1f = (float*)R;                                 // VN*32 fp32 = 100.66 MB
    uint4* t0  = (uint4*)(R + 100663296);                   // VN*16 bf16 = 25.17 MB
    uint4* t1  = (uint4*)(R + 125829120);
    uint4* t2  = (uint4*)(R + 150994944);
    uint4* u0  = (uint4*)R;                                 // VN*32 bf16 = 50.33 MB
    uint4* u1  = (uint4*)(R + 50331648);
    uint4* u2  = (uint4*)(R + 100663296);
    uint4* h1b = (uint4*)p; p += (size_t)VN * FOUT * 2;     // 50.33 MB
    int* row_start = (int*)p; p += (size_t)VN * 4;
    int* cnt       = (int*)p; p += (size_t)VN * 4;
    int* cursor    = (int*)p; p += (size_t)VN * 4;
    int* gcur      = (int*)p;

    hipMemsetAsync(cnt, 0, VN * sizeof(int), stream);
    hipMemsetAsync(gcur, 0, sizeof(int), stream);

    const int B = 256;
    k_count<<<EN / 4 / B, B, 0, stream>>>((const int4*)rows, cnt);
    k_scan <<<VN / B, B, 0, stream>>>(cnt, row_start, cursor, gcur);
    k_fill <<<EN / 4 / B, B, 0, stream>>>((const int4*)rows, (const int4*)cols,
                                          (const float4*)vals, cursor, csr);

    k_cvt<<<VN * FIN / 8 / B, B, 0, stream>>>((const float4*)x, xb);

    const int g16 = VN * 2 / B;   // 6144
    const int g32 = VN * 4 / B;   // 12288

    // ---- layer 1 (F=16), fp32 accum h1f, final bf16 h1b ----
    k_spmm<FIN, true,  false, false, false><<<g16, B, 0, stream>>>(
        row_start, cnt, csr, xb, xb, w1, b1, h1f, t0, nullptr, nullptr, 1);
    k_spmm<FIN, false, false, false, false><<<g16, B, 0, stream>>>(
        row_start, cnt, csr, t0, xb, w1, b1, h1f, t1, nullptr, nullptr, 2);
    k_spmm<FIN, false, false, false, false><<<g16, B, 0, stream>>>(
        row_start, cnt, csr, t1, t0, w1, b1, h1f, t2, nullptr, nullptr, 3);
    k_spmm<FIN, false, true,  true,  false><<<g16, B, 0, stream>>>(
        row_start, cnt, csr, t2, t1, w1, b1, h1f, nullptr, h1b, nullptr, 4); // +ELU ->bf16

    // ---- layer 2 (F=32), accumulate into d_out ----
    k_spmm<FOUT, true,  false, false, false><<<g32, B, 0, stream>>>(
        row_start, cnt, csr, h1b, h1b, w2, b2, out, u0, nullptr, nullptr, 1);
    k_spmm<FOUT, false, false, false, false><<<g32, B, 0, stream>>>(
        row_start, cnt, csr, u0, h1b, w2, b2, out, u1, nullptr, nullptr, 2);
    k_spmm<FOUT, false, false, false, false><<<g32, B, 0, stream>>>(
        row_start, cnt, csr, u1, u0, w2, b2, out, u2, nullptr, nullptr, 3);
    k_spmm<FOUT, false, true,  false, true ><<<g32, B, 0, stream>>>(
        row_start, cnt, csr, u2, u1, w2, b2, out, nullptr, nullptr,
        out + (size_t)VN * FOUT, 4);                                          // +ELU+pool
}